// Round 8
// baseline (67.839 us; speedup 1.0000x reference)
//
#include <hip/hip_runtime.h>
#include <hip/hip_bf16.h>
#include <math.h>

typedef short bf16x8 __attribute__((ext_vector_type(8)));
typedef float f32x4  __attribute__((ext_vector_type(4)));

static __device__ __forceinline__ unsigned short f2bf(float x) {
    unsigned u = __builtin_bit_cast(unsigned, x);
    return (unsigned short)((u + 0x7fffu + ((u >> 16) & 1u)) >> 16);
}

static __device__ __forceinline__ bf16x8 pack8(float4 u0, float4 u1) {
    bf16x8 f;
    f[0] = (short)f2bf(u0.x); f[1] = (short)f2bf(u0.y);
    f[2] = (short)f2bf(u0.z); f[3] = (short)f2bf(u0.w);
    f[4] = (short)f2bf(u1.x); f[5] = (short)f2bf(u1.y);
    f[6] = (short)f2bf(u1.z); f[7] = (short)f2bf(u1.w);
    return f;
}

static __device__ __forceinline__ void async_cp16(const void* gsrc, void* ldsdst) {
    __builtin_amdgcn_global_load_lds(
        (const __attribute__((address_space(1))) void*)gsrc,
        (__attribute__((address_space(3))) void*)ldsdst, 16, 0, 0);
}

// ---- centroid image + c2 + c2bmin + (block ncb: label detect + zero out) ----
// img[cb16][k][lane][j] = cent[cb16*16 + (lane&15)][k*32 + (lane>>4)*8 + j]
__global__ __launch_bounds__(64) void cent_prep_kernel(
    const float* __restrict__ cent, char* __restrict__ Cimg,
    float* __restrict__ c2g, float* __restrict__ c2bmin,
    const unsigned* __restrict__ w, int nelem,
    unsigned* __restrict__ flag, float* __restrict__ out, int out_size, int ncb) {
    const int lane = threadIdx.x;
    if ((int)blockIdx.x < ncb) {
        const int cb = blockIdx.x;
        const int r = cb * 16 + (lane & 15);
        const int q = lane >> 4;
        const float4* C4 = (const float4*)cent;
        float s = 0.0f;
        #pragma unroll
        for (int k = 0; k < 8; ++k) {
            int fidx = r * 64 + k * 8 + q * 2;
            float4 u0 = C4[fidx], u1 = C4[fidx + 1];
            *(bf16x8*)(Cimg + ((size_t)(cb * 8 + k) * 64 + lane) * 16) = pack8(u0, u1);
            s += u0.x*u0.x + u0.y*u0.y + u0.z*u0.z + u0.w*u0.w
               + u1.x*u1.x + u1.y*u1.y + u1.z*u1.z + u1.w*u1.w;
        }
        s += __shfl_xor(s, 16, 64);
        s += __shfl_xor(s, 32, 64);
        if (lane < 16) c2g[cb * 16 + lane] = s;
        float mn = s;
        #pragma unroll
        for (int d = 8; d >= 1; d >>= 1) mn = fminf(mn, __shfl_xor(mn, d, 64));
        if (lane == 0) c2bmin[cb] = mn;
    } else {
        int npairs = nelem / 2; if (npairs > 4096) npairs = 4096;
        unsigned acc = 0;
        for (int i = lane; i < npairs; i += 64) acc |= w[2 * i + 1];
        #pragma unroll
        for (int m = 32; m >= 1; m >>= 1) acc |= __shfl_xor(acc, m, 64);
        if (lane == 0) *flag = (acc != 0u) ? 1u : 0u;   // 1 = int32
        for (int i = lane; i < out_size; i += 64) out[i] = 0.0f;
    }
}

// ---- main: 512 blocks x 64 rows; 8 waves = 2 rowgrp(32) x 4 colq(16 of 64). -
// A in regs (a[2][8], 64 VGPR), B 64-col chunks double-buffered in 64KB LDS ->
// 2 blocks/CU (16 waves/CU) so barrier stalls overlap across blocks. Epilogue
// is a wave-uniform screen: max(acc) vs (e2_wave_min + c2_blockmin - 2)/2;
// exact pos term computed fp32 in the prologue (wc==0 waves).
#define R_BLOCK 64
#define CHUNK_BYTES 32768
#define MAIN_SMEM (2 * CHUNK_BYTES + 64)

__global__ __launch_bounds__(512) void main5_kernel(
    const float* __restrict__ emb, const float* __restrict__ cent,
    const char* __restrict__ Cimg, const float* __restrict__ c2g,
    const float* __restrict__ c2bmin, const int* __restrict__ labw,
    const unsigned* __restrict__ flag, float* __restrict__ out,
    int nchunk, float invB) {
    extern __shared__ char smem[];
    float* red = (float*)(smem + 2 * CHUNK_BYTES);

    const int tid = threadIdx.x, lane = tid & 63, wid = tid >> 6;
    const int wr = wid & 1;        // row group: 32 rows
    const int wc = wid >> 1;       // col quarter: 16 cols of the 64-col chunk
    const int brow0 = blockIdx.x * R_BLOCK;
    const int l15 = lane & 15, q = lane >> 4;

    // fill chunk 0 (async, direct to LDS)
    #pragma unroll
    for (int i = 0; i < 4; ++i)
        async_cp16(Cimg + i * 8192 + tid * 16, smem + i * 8192 + wid * 1024);

    const int is32 = (*flag != 0u);

    // A: 32 rows/wave -> bf16 fragments in regs; e2 per row; exact pos (wc==0).
    bf16x8 a[2][8];
    float e2m[2]; int labv[2];
    float fsum = 0.0f;
    #pragma unroll
    for (int m = 0; m < 2; ++m) {
        const int rg = brow0 + wr * 32 + m * 16 + l15;
        const int lbl = is32 ? labw[rg] : labw[2 * rg];
        labv[m] = lbl;
        const float4* E4 = (const float4*)emb + (size_t)rg * 64;
        const float4* C4 = (const float4*)cent + (size_t)lbl * 64;
        float s = 0.0f, dot = 0.0f, cc = 0.0f;
        #pragma unroll
        for (int k = 0; k < 8; ++k) {
            float4 u0 = E4[k * 8 + q * 2], u1 = E4[k * 8 + q * 2 + 1];
            a[m][k] = pack8(u0, u1);
            s += u0.x*u0.x + u0.y*u0.y + u0.z*u0.z + u0.w*u0.w
               + u1.x*u1.x + u1.y*u1.y + u1.z*u1.z + u1.w*u1.w;
            if (wc == 0) {
                float4 v0 = C4[k * 8 + q * 2], v1 = C4[k * 8 + q * 2 + 1];
                dot += u0.x*v0.x + u0.y*v0.y + u0.z*v0.z + u0.w*v0.w
                     + u1.x*v1.x + u1.y*v1.y + u1.z*v1.z + u1.w*v1.w;
                cc += v0.x*v0.x + v0.y*v0.y + v0.z*v0.z + v0.w*v0.w
                    + v1.x*v1.x + v1.y*v1.y + v1.z*v1.z + v1.w*v1.w;
            }
        }
        s += __shfl_xor(s, 16, 64);
        s += __shfl_xor(s, 32, 64);
        e2m[m] = s;
        if (wc == 0) {
            dot += __shfl_xor(dot, 16, 64); dot += __shfl_xor(dot, 32, 64);
            cc  += __shfl_xor(cc, 16, 64);  cc  += __shfl_xor(cc, 32, 64);
            if (lane < 16) fsum += fmaxf(s + cc - 2.0f * dot, 0.0f);  // pos
        }
    }
    // wave-min of e2 over its 32 rows (wave-uniform)
    float emin = fminf(e2m[0], e2m[1]);
    #pragma unroll
    for (int d = 8; d >= 1; d >>= 1) emin = fminf(emin, __shfl_xor(emin, d, 64));

    for (int ch = 0; ch < nchunk; ++ch) {
        // my fills for chunk ch must have landed; everyone done reading ch-1
        asm volatile("s_waitcnt vmcnt(0)" ::: "memory");
        __builtin_amdgcn_s_barrier();

        const char* Bcur = smem + (ch & 1) * CHUNK_BYTES;
        if (ch + 1 < nchunk) {   // fill next chunk into the other buffer
            const char* src = Cimg + (size_t)(ch + 1) * CHUNK_BYTES;
            char* dst = smem + ((ch + 1) & 1) * CHUNK_BYTES;
            #pragma unroll
            for (int i = 0; i < 4; ++i)
                async_cp16(src + i * 8192 + tid * 16, dst + i * 8192 + wid * 1024);
        }

        f32x4 acc0 = (f32x4){0.0f, 0.0f, 0.0f, 0.0f};
        f32x4 acc1 = (f32x4){0.0f, 0.0f, 0.0f, 0.0f};
        const char* Bw = Bcur + wc * 8192 + lane * 16;
        #pragma unroll
        for (int k = 0; k < 8; ++k) {
            bf16x8 bn = *(const bf16x8*)(Bw + k * 1024);
            acc0 = __builtin_amdgcn_mfma_f32_16x16x32_bf16(a[0][k], bn, acc0, 0, 0, 0);
            acc1 = __builtin_amdgcn_mfma_f32_16x16x32_bf16(a[1][k], bn, acc1, 0, 0, 0);
        }

        // screen: d2 < 2 possible only if dot > (e2min + c2min - 2)/2
        float th = 0.5f * (emin + c2bmin[ch * 4 + wc] - 2.0f);
        float mx = fmaxf(fmaxf(fmaxf(acc0[0], acc0[1]), fmaxf(acc0[2], acc0[3])),
                         fmaxf(fmaxf(acc1[0], acc1[1]), fmaxf(acc1[2], acc1[3])));
        if (__builtin_expect(__any(mx > th), 0)) {   // rare: exact recompute
            int colg = ch * 64 + wc * 16 + l15;
            float c2c = c2g[colg];
            #pragma unroll
            for (int m = 0; m < 2; ++m)
                #pragma unroll
                for (int r = 0; r < 4; ++r) {
                    float dv = (m == 0) ? acc0[r] : acc1[r];
                    float e2r = __shfl(e2m[m], q * 4 + r, 64);
                    int lb = __shfl(labv[m], q * 4 + r, 64);
                    float d2 = fmaxf(e2r + c2c - 2.0f * dv, 0.0f);
                    if (d2 < 1.0f && colg != lb) {
                        float t = 1.0f - sqrtf(d2);
                        fsum += t * t;
                    }
                }
        }
    }

    // block reduction + one atomic
    #pragma unroll
    for (int m = 32; m >= 1; m >>= 1) fsum += __shfl_xor(fsum, m, 64);
    __syncthreads();
    if (lane == 0) red[wid] = fsum;
    __syncthreads();
    if (tid == 0) {
        float t = 0.0f;
        #pragma unroll
        for (int w = 0; w < 8; ++w) t += red[w];
        atomicAdd(out, t * invB);
    }
}

// ======================= fallback (round-1, verified) ========================
#define FB_THREADS 512
#define FB_SMEM 132672
__device__ int g_lab_is64;

__global__ void fb_detect_kernel(const unsigned* __restrict__ w, int nelem,
                                 float* __restrict__ out, int out_size) {
    __shared__ unsigned red[256];
    unsigned acc = 0;
    for (int i = threadIdx.x; i < nelem / 2; i += 256) acc |= w[2 * i + 1];
    red[threadIdx.x] = acc;
    __syncthreads();
    for (int s = 128; s > 0; s >>= 1) {
        if (threadIdx.x < s) red[threadIdx.x] |= red[threadIdx.x + s];
        __syncthreads();
    }
    if (threadIdx.x == 0) g_lab_is64 = (red[0] == 0u) ? 1 : 0;
    for (int i = threadIdx.x; i < out_size; i += 256) out[i] = 0.0f;
}

__global__ __launch_bounds__(FB_THREADS) void fb_loss_kernel(
    const float* __restrict__ emb, const float* __restrict__ cent,
    const int* __restrict__ labw, float* __restrict__ out,
    int nchunk, float invB) {
    extern __shared__ char smem[];
    char* Abf = smem;
    char* Cbf = smem + 65536;
    float* e2 = (float*)(smem + 131072);
    float* c2 = (float*)(smem + 131584);
    int* lab = (int*)(smem + 132096);
    float* red = (float*)(smem + 132608);

    const int tid = threadIdx.x, lane = tid & 63, wid = tid >> 6;
    const int row0 = blockIdx.x * 128;
    const int is64 = g_lab_is64;

    for (int j = 0; j < 16; ++j) {
        int f4 = tid + j * FB_THREADS;
        int r = f4 >> 6, c4 = f4 & 63;
        float4 v = ((const float4*)emb)[(size_t)(row0 + r) * 64 + c4];
        ushort4 h;
        h.x = f2bf(v.x); h.y = f2bf(v.y); h.z = f2bf(v.z); h.w = f2bf(v.w);
        int off = (c4 * 8) ^ ((r & 7) << 4);
        *(ushort4*)(Abf + r * 512 + off) = h;
        float s = v.x*v.x + v.y*v.y + v.z*v.z + v.w*v.w;
        #pragma unroll
        for (int m = 32; m >= 1; m >>= 1) s += __shfl_xor(s, m, 64);
        if (lane == 0) e2[r] = s;
    }
    if (tid < 128) {
        int b = row0 + tid;
        lab[tid] = is64 ? labw[2 * b] : labw[b];
    }
    __syncthreads();

    const int wr = wid >> 1, wc = wid & 1;
    const int l15 = lane & 15, l16 = lane >> 4;
    const int swz = (l15 & 7) << 4;

    float e2v[2][4]; int labv[2][4];
    #pragma unroll
    for (int m = 0; m < 2; ++m)
        #pragma unroll
        for (int r = 0; r < 4; ++r) {
            int rr = wr * 32 + m * 16 + l16 * 4 + r;
            e2v[m][r] = e2[rr]; labv[m][r] = lab[rr];
        }

    float fsum = 0.0f;
    for (int ch = 0; ch < nchunk; ++ch) {
        const float* cbase = cent + (size_t)ch * 128 * 256;
        for (int j = 0; j < 16; ++j) {
            int f4 = tid + j * FB_THREADS;
            int r = f4 >> 6, c4 = f4 & 63;
            float4 v = ((const float4*)cbase)[(size_t)r * 64 + c4];
            ushort4 h;
            h.x = f2bf(v.x); h.y = f2bf(v.y); h.z = f2bf(v.z); h.w = f2bf(v.w);
            int off = (c4 * 8) ^ ((r & 7) << 4);
            *(ushort4*)(Cbf + r * 512 + off) = h;
            float s = v.x*v.x + v.y*v.y + v.z*v.z + v.w*v.w;
            #pragma unroll
            for (int m = 32; m >= 1; m >>= 1) s += __shfl_xor(s, m, 64);
            if (lane == 0) c2[r] = s;
        }
        __syncthreads();

        f32x4 acc[2][4];
        #pragma unroll
        for (int m = 0; m < 2; ++m)
            #pragma unroll
            for (int n = 0; n < 4; ++n) acc[m][n] = (f32x4){0, 0, 0, 0};

        #pragma unroll
        for (int kk = 0; kk < 8; ++kk) {
            int kb = kk * 64 + l16 * 16;
            bf16x8 a[2], b[4];
            #pragma unroll
            for (int m = 0; m < 2; ++m)
                a[m] = *(const bf16x8*)(Abf + (wr * 32 + m * 16 + l15) * 512 + (kb ^ swz));
            #pragma unroll
            for (int n = 0; n < 4; ++n)
                b[n] = *(const bf16x8*)(Cbf + (wc * 64 + n * 16 + l15) * 512 + (kb ^ swz));
            #pragma unroll
            for (int m = 0; m < 2; ++m)
                #pragma unroll
                for (int n = 0; n < 4; ++n)
                    acc[m][n] = __builtin_amdgcn_mfma_f32_16x16x32_bf16(a[m], b[n], acc[m][n], 0, 0, 0);
        }

        float c2v[4]; int colg[4];
        #pragma unroll
        for (int n = 0; n < 4; ++n) {
            int cl = wc * 64 + n * 16 + l15;
            c2v[n] = c2[cl]; colg[n] = ch * 128 + cl;
        }
        unsigned need = 0;
        #pragma unroll
        for (int m = 0; m < 2; ++m)
            #pragma unroll
            for (int n = 0; n < 4; ++n)
                #pragma unroll
                for (int r = 0; r < 4; ++r) {
                    float d2 = fmaf(-2.0f, acc[m][n][r], e2v[m][r] + c2v[n]);
                    d2 = fmaxf(d2, 0.0f);
                    bool isp = (colg[n] == labv[m][r]);
                    fsum += isp ? d2 : 0.0f;
                    need |= (unsigned)((!isp) & (d2 < 1.0f)) << (m * 16 + n * 4 + r);
                }
        if (__any(need != 0)) {
            #pragma unroll
            for (int m = 0; m < 2; ++m)
                #pragma unroll
                for (int n = 0; n < 4; ++n)
                    #pragma unroll
                    for (int r = 0; r < 4; ++r)
                        if ((need >> (m * 16 + n * 4 + r)) & 1u) {
                            float d2 = fmaf(-2.0f, acc[m][n][r], e2v[m][r] + c2v[n]);
                            d2 = fmaxf(d2, 0.0f);
                            float t = 1.0f - sqrtf(d2);
                            fsum += t * t;
                        }
        }
        __syncthreads();
    }
    #pragma unroll
    for (int m = 32; m >= 1; m >>= 1) fsum += __shfl_xor(fsum, m, 64);
    if (lane == 0) red[wid] = fsum;
    __syncthreads();
    if (tid == 0) {
        float t = 0.0f;
        #pragma unroll
        for (int w = 0; w < 8; ++w) t += red[w];
        atomicAdd(out, t * invB);
    }
}

// =============================================================================
extern "C" void kernel_launch(void* const* d_in, const int* in_sizes, int n_in,
                              void* d_out, int out_size, void* d_ws, size_t ws_size,
                              hipStream_t stream) {
    const float* emb = (const float*)d_in[0];
    const float* cent = (const float*)d_in[1];
    const int* labw = (const int*)d_in[2];
    float* out = (float*)d_out;

    const int B = in_sizes[0] / 256;
    const int K = in_sizes[1] / 256;
    const float invB = 1.0f / (float)B;

    char* ws = (char*)d_ws;
    const size_t off_flag = 0;
    const size_t off_c2bmin = 256;       // K/16 floats
    const size_t off_c2 = 8192;          // K floats
    const size_t off_cimg = 16384;
    const size_t req = off_cimg + (size_t)K * 512;

    if (ws_size >= req) {
        const int ncb = K / 16;          // 64 centroid-image blocks
        cent_prep_kernel<<<ncb + 1, 64, 0, stream>>>(
            cent, ws + off_cimg, (float*)(ws + off_c2), (float*)(ws + off_c2bmin),
            (const unsigned*)d_in[2], in_sizes[2], (unsigned*)(ws + off_flag),
            out, out_size, ncb);

        hipFuncSetAttribute(reinterpret_cast<const void*>(main5_kernel),
                            hipFuncAttributeMaxDynamicSharedMemorySize, MAIN_SMEM);
        main5_kernel<<<B / R_BLOCK, 512, MAIN_SMEM, stream>>>(
            emb, cent, ws + off_cimg, (const float*)(ws + off_c2),
            (const float*)(ws + off_c2bmin), labw,
            (const unsigned*)(ws + off_flag), out, K / 64, invB);
    } else {
        fb_detect_kernel<<<1, 256, 0, stream>>>((const unsigned*)d_in[2], in_sizes[2],
                                                out, out_size);
        hipFuncSetAttribute(reinterpret_cast<const void*>(fb_loss_kernel),
                            hipFuncAttributeMaxDynamicSharedMemorySize, FB_SMEM);
        fb_loss_kernel<<<B / 128, FB_THREADS, FB_SMEM, stream>>>(
            emb, cent, labw, out, K / 128, invB);
    }
}

// Round 9
// 56.913 us; speedup vs baseline: 1.1920x; 1.1920x over previous
//
#include <hip/hip_runtime.h>
#include <hip/hip_bf16.h>
#include <math.h>

typedef short bf16x8 __attribute__((ext_vector_type(8)));
typedef float f32x4  __attribute__((ext_vector_type(4)));

static __device__ __forceinline__ unsigned short f2bf(float x) {
    unsigned u = __builtin_bit_cast(unsigned, x);
    return (unsigned short)((u + 0x7fffu + ((u >> 16) & 1u)) >> 16);
}

static __device__ __forceinline__ bf16x8 pack8(float4 u0, float4 u1) {
    bf16x8 f;
    f[0] = (short)f2bf(u0.x); f[1] = (short)f2bf(u0.y);
    f[2] = (short)f2bf(u0.z); f[3] = (short)f2bf(u0.w);
    f[4] = (short)f2bf(u1.x); f[5] = (short)f2bf(u1.y);
    f[6] = (short)f2bf(u1.z); f[7] = (short)f2bf(u1.w);
    return f;
}

static __device__ __forceinline__ void async_cp16(const void* gsrc, void* ldsdst) {
    __builtin_amdgcn_global_load_lds(
        (const __attribute__((address_space(1))) void*)gsrc,
        (__attribute__((address_space(3))) void*)ldsdst, 16, 0, 0);
}

// ---- centroid image + c2 + c2bmin + (block ncb: label detect + zero out) ----
// img[cb16][k][lane][j] = cent[cb16*16 + (lane&15)][k*32 + (lane>>4)*8 + j]
__global__ __launch_bounds__(64) void cent_prep_kernel(
    const float* __restrict__ cent, char* __restrict__ Cimg,
    float* __restrict__ c2g, float* __restrict__ c2bmin,
    const unsigned* __restrict__ w, int nelem,
    unsigned* __restrict__ flag, float* __restrict__ out, int out_size, int ncb) {
    const int lane = threadIdx.x;
    if ((int)blockIdx.x < ncb) {
        const int cb = blockIdx.x;
        const int r = cb * 16 + (lane & 15);
        const int q = lane >> 4;
        const float4* C4 = (const float4*)cent;
        float s = 0.0f;
        #pragma unroll
        for (int k = 0; k < 8; ++k) {
            int fidx = r * 64 + k * 8 + q * 2;
            float4 u0 = C4[fidx], u1 = C4[fidx + 1];
            *(bf16x8*)(Cimg + ((size_t)(cb * 8 + k) * 64 + lane) * 16) = pack8(u0, u1);
            s += u0.x*u0.x + u0.y*u0.y + u0.z*u0.z + u0.w*u0.w
               + u1.x*u1.x + u1.y*u1.y + u1.z*u1.z + u1.w*u1.w;
        }
        s += __shfl_xor(s, 16, 64);
        s += __shfl_xor(s, 32, 64);
        if (lane < 16) c2g[cb * 16 + lane] = s;
        float mn = s;
        #pragma unroll
        for (int d = 8; d >= 1; d >>= 1) mn = fminf(mn, __shfl_xor(mn, d, 64));
        if (lane == 0) c2bmin[cb] = mn;
    } else {
        int npairs = nelem / 2; if (npairs > 4096) npairs = 4096;
        unsigned acc = 0;
        for (int i = lane; i < npairs; i += 64) acc |= w[2 * i + 1];
        #pragma unroll
        for (int m = 32; m >= 1; m >>= 1) acc |= __shfl_xor(acc, m, 64);
        if (lane == 0) *flag = (acc != 0u) ? 1u : 0u;   // 1 = int32
        for (int i = lane; i < out_size; i += 64) out[i] = 0.0f;
    }
}

// ---- embedding pre-pass: bf16 fragment image + e2 + lab32 + exact pos sum ---
// Abf[rb16][k][lane][j] = emb[rb16*16 + (lane&15)][k*32 + (lane>>4)*8 + j]
// Per-k a wave reads 16 rows x 128 contiguous bytes (coalesced).
__global__ __launch_bounds__(256) void emb_prep_kernel(
    const float* __restrict__ emb, const float* __restrict__ cent,
    const int* __restrict__ labw, const unsigned* __restrict__ flag,
    char* __restrict__ Abf, float* __restrict__ e2g, int* __restrict__ lab32,
    float* __restrict__ out, float invB) {
    __shared__ float red[4];
    const int tid = threadIdx.x, lane = tid & 63, wv = tid >> 6;
    const int rb16 = blockIdx.x * 4 + wv;
    const int r = lane & 15, q = lane >> 4;
    const int row = rb16 * 16 + r;
    const int is32 = (*flag != 0u);
    const int lbl = is32 ? labw[row] : labw[2 * row];
    const float4* E4 = (const float4*)emb + (size_t)row * 64;
    const float4* C4 = (const float4*)cent + (size_t)lbl * 64;
    float s = 0.0f, dot = 0.0f, cc = 0.0f;
    #pragma unroll
    for (int k = 0; k < 8; ++k) {
        float4 u0 = E4[k * 8 + q * 2], u1 = E4[k * 8 + q * 2 + 1];
        *(bf16x8*)(Abf + ((size_t)(rb16 * 8 + k) * 64 + lane) * 16) = pack8(u0, u1);
        s += u0.x*u0.x + u0.y*u0.y + u0.z*u0.z + u0.w*u0.w
           + u1.x*u1.x + u1.y*u1.y + u1.z*u1.z + u1.w*u1.w;
        float4 v0 = C4[k * 8 + q * 2], v1 = C4[k * 8 + q * 2 + 1];
        dot += u0.x*v0.x + u0.y*v0.y + u0.z*v0.z + u0.w*v0.w
             + u1.x*v1.x + u1.y*v1.y + u1.z*v1.z + u1.w*v1.w;
        cc += v0.x*v0.x + v0.y*v0.y + v0.z*v0.z + v0.w*v0.w
            + v1.x*v1.x + v1.y*v1.y + v1.z*v1.z + v1.w*v1.w;
    }
    s += __shfl_xor(s, 16, 64);   s += __shfl_xor(s, 32, 64);
    dot += __shfl_xor(dot, 16, 64); dot += __shfl_xor(dot, 32, 64);
    cc += __shfl_xor(cc, 16, 64);  cc += __shfl_xor(cc, 32, 64);
    float pos = 0.0f;
    if (q == 0) {                 // lanes 0..15: one per row
        e2g[row] = s;
        lab32[row] = lbl;
        float d2 = fmaxf(s + cc - 2.0f * dot, 0.0f);
        pos = d2;
        if (d2 < 1.0f) { float t = 1.0f - sqrtf(d2); pos -= t * t; }
    }
    #pragma unroll
    for (int m = 32; m >= 1; m >>= 1) pos += __shfl_xor(pos, m, 64);
    if (lane == 0) red[wv] = pos;
    __syncthreads();
    if (tid == 0)
        atomicAdd(out, (red[0] + red[1] + red[2] + red[3]) * invB);
}

// ---- main: 256 thr / 4 waves; block = 64 rows; wave = 64 rows x 16 cols. ----
// A fragments a[4][8] loaded straight from the pre-converted Abf image (no
// conversion VALU). B: 64-col chunks (32KB) double-buffered via global_load_lds
// -> 2 blocks/CU. 4 MFMA per ds_read_b128. launch_bounds(256,1) unlocks the
// 256-VGPR budget (512-thr blocks empirically cap at 128 and spill).
#define CHUNK_BYTES 32768
#define MAIN_SMEM (2 * CHUNK_BYTES + 64)

__global__ __launch_bounds__(256, 1) void main6_kernel(
    const char* __restrict__ Abf, const char* __restrict__ Cimg,
    const float* __restrict__ e2g, const float* __restrict__ c2g,
    const float* __restrict__ c2bmin, const int* __restrict__ lab32,
    float* __restrict__ out, int nchunk, float invB) {
    extern __shared__ char smem[];
    float* red = (float*)(smem + 2 * CHUNK_BYTES);

    const int tid = threadIdx.x, lane = tid & 63, wid = tid >> 6;  // wid = col16
    const int bid = blockIdx.x;
    const int l15 = lane & 15, q = lane >> 4;

    // fill chunk 0 (async, direct to LDS)
    #pragma unroll
    for (int i = 0; i < 8; ++i)
        async_cp16(Cimg + (size_t)(i * 256 + tid) * 16, smem + (i * 256 + tid) * 16);

    // A: 4 row-groups x 8 k-fragments, straight 16B loads from the image
    bf16x8 a[4][8];
    #pragma unroll
    for (int m = 0; m < 4; ++m)
        #pragma unroll
        for (int k = 0; k < 8; ++k)
            a[m][k] = *(const bf16x8*)(Abf +
                ((size_t)((bid * 4 + m) * 8 + k) * 64 + lane) * 16);

    // per-row metadata (one row per lane), wave-uniform screen inputs
    const float e2v = e2g[bid * 64 + lane];
    const int   labv = lab32[bid * 64 + lane];
    float emin = e2v;
    #pragma unroll
    for (int d = 32; d >= 1; d >>= 1) emin = fminf(emin, __shfl_xor(emin, d, 64));
    const float thc = (lane < 16) ? c2bmin[lane * 4 + wid] : 3.0e38f;

    float fsum = 0.0f;

    for (int ch = 0; ch < nchunk; ++ch) {
        asm volatile("s_waitcnt vmcnt(0)" ::: "memory");
        __builtin_amdgcn_s_barrier();

        const char* Bcur = smem + (ch & 1) * CHUNK_BYTES;
        if (ch + 1 < nchunk) {
            const char* src = Cimg + (size_t)(ch + 1) * CHUNK_BYTES;
            char* dst = smem + ((ch + 1) & 1) * CHUNK_BYTES;
            #pragma unroll
            for (int i = 0; i < 8; ++i)
                async_cp16(src + (size_t)(i * 256 + tid) * 16, dst + (i * 256 + tid) * 16);
        }

        f32x4 acc[4];
        #pragma unroll
        for (int m = 0; m < 4; ++m) acc[m] = (f32x4){0.0f, 0.0f, 0.0f, 0.0f};
        const char* Bw = Bcur + wid * 8192 + lane * 16;
        #pragma unroll
        for (int k = 0; k < 8; ++k) {
            bf16x8 b = *(const bf16x8*)(Bw + k * 1024);
            #pragma unroll
            for (int m = 0; m < 4; ++m)
                acc[m] = __builtin_amdgcn_mfma_f32_16x16x32_bf16(a[m][k], b, acc[m], 0, 0, 0);
        }

        // screen: d2 < 2 possible only if dot > (e2min + c2min - 2)/2
        float th = 0.5f * (emin + __shfl(thc, ch, 64) - 2.0f);
        float mx = acc[0][0];
        #pragma unroll
        for (int m = 0; m < 4; ++m)
            #pragma unroll
            for (int r = 0; r < 4; ++r) mx = fmaxf(mx, acc[m][r]);
        if (__builtin_expect(__any(mx > th), 0)) {   // rare: exact recompute
            int colg = ch * 64 + wid * 16 + l15;
            float c2c = c2g[colg];
            #pragma unroll
            for (int m = 0; m < 4; ++m)
                #pragma unroll
                for (int r = 0; r < 4; ++r) {
                    int rowl = m * 16 + q * 4 + r;
                    float e2r = __shfl(e2v, rowl, 64);
                    int lb = __shfl(labv, rowl, 64);
                    float d2 = fmaxf(e2r + c2c - 2.0f * acc[m][r], 0.0f);
                    if (d2 < 1.0f && colg != lb) {
                        float t = 1.0f - sqrtf(d2);
                        fsum += t * t;
                    }
                }
        }
    }

    #pragma unroll
    for (int m = 32; m >= 1; m >>= 1) fsum += __shfl_xor(fsum, m, 64);
    __syncthreads();
    if (lane == 0) red[wid] = fsum;
    __syncthreads();
    if (tid == 0)
        atomicAdd(out, (red[0] + red[1] + red[2] + red[3]) * invB);
}

// ======================= fallback (round-1, verified) ========================
#define FB_THREADS 512
#define FB_SMEM 132672
__device__ int g_lab_is64;

__global__ void fb_detect_kernel(const unsigned* __restrict__ w, int nelem,
                                 float* __restrict__ out, int out_size) {
    __shared__ unsigned red[256];
    unsigned acc = 0;
    for (int i = threadIdx.x; i < nelem / 2; i += 256) acc |= w[2 * i + 1];
    red[threadIdx.x] = acc;
    __syncthreads();
    for (int s = 128; s > 0; s >>= 1) {
        if (threadIdx.x < s) red[threadIdx.x] |= red[threadIdx.x + s];
        __syncthreads();
    }
    if (threadIdx.x == 0) g_lab_is64 = (red[0] == 0u) ? 1 : 0;
    for (int i = threadIdx.x; i < out_size; i += 256) out[i] = 0.0f;
}

__global__ __launch_bounds__(FB_THREADS) void fb_loss_kernel(
    const float* __restrict__ emb, const float* __restrict__ cent,
    const int* __restrict__ labw, float* __restrict__ out,
    int nchunk, float invB) {
    extern __shared__ char smem[];
    char* Abf = smem;
    char* Cbf = smem + 65536;
    float* e2 = (float*)(smem + 131072);
    float* c2 = (float*)(smem + 131584);
    int* lab = (int*)(smem + 132096);
    float* red = (float*)(smem + 132608);

    const int tid = threadIdx.x, lane = tid & 63, wid = tid >> 6;
    const int row0 = blockIdx.x * 128;
    const int is64 = g_lab_is64;

    for (int j = 0; j < 16; ++j) {
        int f4 = tid + j * FB_THREADS;
        int r = f4 >> 6, c4 = f4 & 63;
        float4 v = ((const float4*)emb)[(size_t)(row0 + r) * 64 + c4];
        ushort4 h;
        h.x = f2bf(v.x); h.y = f2bf(v.y); h.z = f2bf(v.z); h.w = f2bf(v.w);
        int off = (c4 * 8) ^ ((r & 7) << 4);
        *(ushort4*)(Abf + r * 512 + off) = h;
        float s = v.x*v.x + v.y*v.y + v.z*v.z + v.w*v.w;
        #pragma unroll
        for (int m = 32; m >= 1; m >>= 1) s += __shfl_xor(s, m, 64);
        if (lane == 0) e2[r] = s;
    }
    if (tid < 128) {
        int b = row0 + tid;
        lab[tid] = is64 ? labw[2 * b] : labw[b];
    }
    __syncthreads();

    const int wr = wid >> 1, wc = wid & 1;
    const int l15 = lane & 15, l16 = lane >> 4;
    const int swz = (l15 & 7) << 4;

    float e2v[2][4]; int labv[2][4];
    #pragma unroll
    for (int m = 0; m < 2; ++m)
        #pragma unroll
        for (int r = 0; r < 4; ++r) {
            int rr = wr * 32 + m * 16 + l16 * 4 + r;
            e2v[m][r] = e2[rr]; labv[m][r] = lab[rr];
        }

    float fsum = 0.0f;
    for (int ch = 0; ch < nchunk; ++ch) {
        const float* cbase = cent + (size_t)ch * 128 * 256;
        for (int j = 0; j < 16; ++j) {
            int f4 = tid + j * FB_THREADS;
            int r = f4 >> 6, c4 = f4 & 63;
            float4 v = ((const float4*)cbase)[(size_t)r * 64 + c4];
            ushort4 h;
            h.x = f2bf(v.x); h.y = f2bf(v.y); h.z = f2bf(v.z); h.w = f2bf(v.w);
            int off = (c4 * 8) ^ ((r & 7) << 4);
            *(ushort4*)(Cbf + r * 512 + off) = h;
            float s = v.x*v.x + v.y*v.y + v.z*v.z + v.w*v.w;
            #pragma unroll
            for (int m = 32; m >= 1; m >>= 1) s += __shfl_xor(s, m, 64);
            if (lane == 0) c2[r] = s;
        }
        __syncthreads();

        f32x4 acc[2][4];
        #pragma unroll
        for (int m = 0; m < 2; ++m)
            #pragma unroll
            for (int n = 0; n < 4; ++n) acc[m][n] = (f32x4){0, 0, 0, 0};

        #pragma unroll
        for (int kk = 0; kk < 8; ++kk) {
            int kb = kk * 64 + l16 * 16;
            bf16x8 a[2], b[4];
            #pragma unroll
            for (int m = 0; m < 2; ++m)
                a[m] = *(const bf16x8*)(Abf + (wr * 32 + m * 16 + l15) * 512 + (kb ^ swz));
            #pragma unroll
            for (int n = 0; n < 4; ++n)
                b[n] = *(const bf16x8*)(Cbf + (wc * 64 + n * 16 + l15) * 512 + (kb ^ swz));
            #pragma unroll
            for (int m = 0; m < 2; ++m)
                #pragma unroll
                for (int n = 0; n < 4; ++n)
                    acc[m][n] = __builtin_amdgcn_mfma_f32_16x16x32_bf16(a[m], b[n], acc[m][n], 0, 0, 0);
        }

        float c2v[4]; int colg[4];
        #pragma unroll
        for (int n = 0; n < 4; ++n) {
            int cl = wc * 64 + n * 16 + l15;
            c2v[n] = c2[cl]; colg[n] = ch * 128 + cl;
        }
        unsigned need = 0;
        #pragma unroll
        for (int m = 0; m < 2; ++m)
            #pragma unroll
            for (int n = 0; n < 4; ++n)
                #pragma unroll
                for (int r = 0; r < 4; ++r) {
                    float d2 = fmaf(-2.0f, acc[m][n][r], e2v[m][r] + c2v[n]);
                    d2 = fmaxf(d2, 0.0f);
                    bool isp = (colg[n] == labv[m][r]);
                    fsum += isp ? d2 : 0.0f;
                    need |= (unsigned)((!isp) & (d2 < 1.0f)) << (m * 16 + n * 4 + r);
                }
        if (__any(need != 0)) {
            #pragma unroll
            for (int m = 0; m < 2; ++m)
                #pragma unroll
                for (int n = 0; n < 4; ++n)
                    #pragma unroll
                    for (int r = 0; r < 4; ++r)
                        if ((need >> (m * 16 + n * 4 + r)) & 1u) {
                            float d2 = fmaf(-2.0f, acc[m][n][r], e2v[m][r] + c2v[n]);
                            d2 = fmaxf(d2, 0.0f);
                            float t = 1.0f - sqrtf(d2);
                            fsum += t * t;
                        }
        }
        __syncthreads();
    }
    #pragma unroll
    for (int m = 32; m >= 1; m >>= 1) fsum += __shfl_xor(fsum, m, 64);
    if (lane == 0) red[wid] = fsum;
    __syncthreads();
    if (tid == 0) {
        float t = 0.0f;
        #pragma unroll
        for (int w = 0; w < 8; ++w) t += red[w];
        atomicAdd(out, t * invB);
    }
}

// =============================================================================
extern "C" void kernel_launch(void* const* d_in, const int* in_sizes, int n_in,
                              void* d_out, int out_size, void* d_ws, size_t ws_size,
                              hipStream_t stream) {
    const float* emb = (const float*)d_in[0];
    const float* cent = (const float*)d_in[1];
    const int* labw = (const int*)d_in[2];
    float* out = (float*)d_out;

    const int B = in_sizes[0] / 256;
    const int K = in_sizes[1] / 256;
    const float invB = 1.0f / (float)B;

    char* ws = (char*)d_ws;
    const size_t off_flag = 0;
    const size_t off_c2bmin = 256;                         // K/16 floats
    const size_t off_c2 = 4096;                            // K floats
    const size_t off_e2 = 16384;                           // B floats
    const size_t off_lab = off_e2 + (size_t)B * 4;         // B ints
    const size_t off_cimg = (off_lab + (size_t)B * 4 + 4095) & ~(size_t)4095;
    const size_t off_abf = off_cimg + (size_t)K * 512;     // K*512 B image
    const size_t req = off_abf + (size_t)B * 512;

    if (ws_size >= req) {
        const int ncb = K / 16;                            // 64 image blocks
        cent_prep_kernel<<<ncb + 1, 64, 0, stream>>>(
            cent, ws + off_cimg, (float*)(ws + off_c2), (float*)(ws + off_c2bmin),
            (const unsigned*)d_in[2], in_sizes[2], (unsigned*)(ws + off_flag),
            out, out_size, ncb);

        emb_prep_kernel<<<B / 64, 256, 0, stream>>>(
            emb, cent, labw, (const unsigned*)(ws + off_flag),
            ws + off_abf, (float*)(ws + off_e2), (int*)(ws + off_lab),
            out, invB);

        hipFuncSetAttribute(reinterpret_cast<const void*>(main6_kernel),
                            hipFuncAttributeMaxDynamicSharedMemorySize, MAIN_SMEM);
        main6_kernel<<<B / 64, 256, MAIN_SMEM, stream>>>(
            ws + off_abf, ws + off_cimg, (const float*)(ws + off_e2),
            (const float*)(ws + off_c2), (const float*)(ws + off_c2bmin),
            (const int*)(ws + off_lab), out, K / 64, invB);
    } else {
        fb_detect_kernel<<<1, 256, 0, stream>>>((const unsigned*)d_in[2], in_sizes[2],
                                                out, out_size);
        hipFuncSetAttribute(reinterpret_cast<const void*>(fb_loss_kernel),
                            hipFuncAttributeMaxDynamicSharedMemorySize, FB_SMEM);
        fb_loss_kernel<<<B / 128, FB_THREADS, FB_SMEM, stream>>>(
            emb, cent, labw, out, K / 128, invB);
    }
}